// Round 1
// baseline (69.805 us; speedup 1.0000x reference)
//
#include <hip/hip_runtime.h>
#include <stdint.h>

#define AS_G __attribute__((address_space(1)))
#define AS_L __attribute__((address_space(3)))

typedef __bf16 bf16x8 __attribute__((ext_vector_type(8)));
typedef float  f32x4  __attribute__((ext_vector_type(4)));

static constexpr int NIMG = 16, CIN = 128, H = 64, W = 64, OCH = 128;
static constexpr int HO = 62, WO = 62;
static constexpr int PIX = HO * WO;            // 3844
static constexpr int M_TOT = NIMG * PIX;       // 61504
static constexpr int K_TOT = CIN * 9;          // 1152
static constexpr int BM = 128, BK = 64;
static constexpr int KSTEPS = K_TOT / BK;      // 18

__device__ __forceinline__ unsigned short f2bf(float f) {
    union { float f; uint32_t u; } v; v.f = f;
    uint32_t u = v.u;
    return (unsigned short)((u + 0x7FFFu + ((u >> 16) & 1u)) >> 16);
}

// NCHW fp32 -> NHWC bf16. One block per (n,h) row.
__global__ __launch_bounds__(256) void xpose_kernel(const float* __restrict__ x,
                                                    unsigned short* __restrict__ xt) {
    __shared__ float lds[CIN][W + 4];   // pad 64->68 (16B-aligned rows, spreads banks)
    const int n   = blockIdx.x >> 6;
    const int h   = blockIdx.x & 63;
    const int tid = threadIdx.x;
    {
        const int c  = tid >> 1;
        const int w0 = (tid & 1) * 32;
        const float* src = x + (((size_t)(n * CIN + c) * H + h) * W + w0);
        #pragma unroll
        for (int j = 0; j < 8; ++j) {
            float4 v = *reinterpret_cast<const float4*>(src + j * 4);
            *reinterpret_cast<float4*>(&lds[c][w0 + j * 4]) = v;
        }
    }
    __syncthreads();
    {
        const int w  = tid >> 2;
        const int c0 = (tid & 3) * 32;
        unsigned short* dst = xt + (((size_t)(n * H + h) * W + w) * CIN + c0);
        uint32_t pk[16];
        #pragma unroll
        for (int j = 0; j < 16; ++j) {
            uint32_t lo = f2bf(lds[c0 + 2 * j][w]);
            uint32_t hi = f2bf(lds[c0 + 2 * j + 1][w]);
            pk[j] = lo | (hi << 16);
        }
        #pragma unroll
        for (int j = 0; j < 4; ++j) {
            *reinterpret_cast<uint4*>(dst + j * 8) =
                make_uint4(pk[4 * j], pk[4 * j + 1], pk[4 * j + 2], pk[4 * j + 3]);
        }
    }
}

// weight [O][c*9+t] fp32 -> Bp [O][t*128+c] bf16 (row-major, o-major)
__global__ __launch_bounds__(256) void wprep_kernel(const float* __restrict__ wsrc,
                                                    unsigned short* __restrict__ bpd) {
    int tid = blockIdx.x * 256 + threadIdx.x;
    if (tid >= OCH * K_TOT) return;
    int o  = tid / K_TOT;
    int kp = tid - o * K_TOT;   // kp = t*128 + c
    int t  = kp >> 7;
    int c  = kp & 127;
    bpd[tid] = f2bf(wsrc[o * K_TOT + c * 9 + t]);
}

// Implicit-GEMM conv: C[m][o] = sum_k A[m][k]*W[o][k], m=(n,y,x), k=(t,c)
__global__ __launch_bounds__(256) void gemm_kernel(const unsigned short* __restrict__ xt,
                                                   const unsigned short* __restrict__ bp,
                                                   const float* __restrict__ bias,
                                                   float* __restrict__ out) {
    __shared__ alignas(16) unsigned short As[BM * BK];   // 16 KB, XOR-swizzled layout
    __shared__ alignas(16) unsigned short Bs[OCH * BK];  // 16 KB
    const int tid  = threadIdx.x;
    const int wv   = tid >> 6;
    const int lane = tid & 63;
    const int m0   = blockIdx.x * BM;

    // ---- staging geometry ----
    // slot s = (wv*4+i)*64 + lane covers LDS bytes [s*16, s*16+16); row = s>>3.
    // logical layout: phys_byte = row*128 + (colbyte ^ ((row&7)<<4));
    // row&7 == lane>>3, so the source column offset (elements) is:
    const int csel = ((lane & 7) ^ (lane >> 3)) * 8;
    int aBase[4], bBase[4];
    #pragma unroll
    for (int i = 0; i < 4; ++i) {
        int row = (wv * 4 + i) * 8 + (lane >> 3);
        int m = m0 + row; if (m >= M_TOT) m = 0;     // clamp: garbage rows never stored
        int n  = m / PIX;
        int r  = m - n * PIX;
        int y  = r / WO;
        int xx = r - y * WO;
        aBase[i] = ((n * H + y) * W + xx) * CIN;     // NHWC elem index, tap 0
        bBase[i] = row * K_TOT;                      // o-row in Bp
    }

    // ---- compute-side fragment addresses ----
    const int wr = wv >> 1, wc = wv & 1;
    const int lr = lane & 15, lq = lane >> 4;
    const int aRow = (wr * 64 + lr) * 128;           // byte offset of row
    const int bRow = (wc * 64 + lr) * 128;
    int colx[2];
    #pragma unroll
    for (int ks = 0; ks < 2; ++ks)
        colx[ks] = (ks * 64 + lq * 16) ^ ((lane & 7) << 4);   // swizzled col byte

    f32x4 acc[4][4];
    #pragma unroll
    for (int a = 0; a < 4; ++a)
        #pragma unroll
        for (int b = 0; b < 4; ++b)
            acc[a][b] = (f32x4){0.f, 0.f, 0.f, 0.f};

    const char* AsB = (const char*)As;
    const char* BsB = (const char*)Bs;

    for (int step = 0; step < KSTEPS; ++step) {
        const int t  = step >> 1;
        const int c0 = (step & 1) * 64;
        const int tapoff = (t / 3) * (W * CIN) + (t % 3) * CIN + c0;  // elems
        const int kb = step * BK;
        #pragma unroll
        for (int i = 0; i < 4; ++i) {
            __builtin_amdgcn_global_load_lds(
                (AS_G unsigned int*)(xt + aBase[i] + tapoff + csel),
                (AS_L unsigned int*)((char*)As + (wv * 4 + i) * 1024),
                16, 0, 0);
            __builtin_amdgcn_global_load_lds(
                (AS_G unsigned int*)(bp + bBase[i] + kb + csel),
                (AS_L unsigned int*)((char*)Bs + (wv * 4 + i) * 1024),
                16, 0, 0);
        }
        __syncthreads();   // compiler drains vmcnt before barrier
        #pragma unroll
        for (int ks = 0; ks < 2; ++ks) {
            bf16x8 af[4], bfr[4];
            #pragma unroll
            for (int mi = 0; mi < 4; ++mi)
                af[mi] = *(const bf16x8*)(AsB + aRow + mi * 2048 + colx[ks]);
            #pragma unroll
            for (int ni = 0; ni < 4; ++ni)
                bfr[ni] = *(const bf16x8*)(BsB + bRow + ni * 2048 + colx[ks]);
            #pragma unroll
            for (int mi = 0; mi < 4; ++mi)
                #pragma unroll
                for (int ni = 0; ni < 4; ++ni)
                    acc[mi][ni] = __builtin_amdgcn_mfma_f32_16x16x32_bf16(
                        af[mi], bfr[ni], acc[mi][ni], 0, 0, 0);
        }
        __syncthreads();
    }

    // ---- epilogue: C/D layout col=lane&15, row=(lane>>4)*4+j ----
    float bv[4];
    #pragma unroll
    for (int ni = 0; ni < 4; ++ni)
        bv[ni] = bias[wc * 64 + ni * 16 + lr];
    #pragma unroll
    for (int mi = 0; mi < 4; ++mi) {
        #pragma unroll
        for (int j = 0; j < 4; ++j) {
            int m = m0 + wr * 64 + mi * 16 + lq * 4 + j;
            if (m < M_TOT) {
                int n  = m / PIX;
                int r  = m - n * PIX;
                int y  = r / WO;
                int xx = r - y * WO;
                float* ob = out + (size_t)n * OCH * PIX + y * WO + xx;
                #pragma unroll
                for (int ni = 0; ni < 4; ++ni) {
                    int o = wc * 64 + ni * 16 + lr;
                    ob[(size_t)o * PIX] = acc[mi][ni][j] + bv[ni];
                }
            }
        }
    }
}

extern "C" void kernel_launch(void* const* d_in, const int* in_sizes, int n_in,
                              void* d_out, int out_size, void* d_ws, size_t ws_size,
                              hipStream_t stream) {
    const float* x    = (const float*)d_in[0];
    const float* wsrc = (const float*)d_in[1];
    const float* bias = (const float*)d_in[2];
    float* out = (float*)d_out;
    unsigned short* xt = (unsigned short*)d_ws;                       // 16 MiB NHWC bf16
    unsigned short* bp = xt + (size_t)NIMG * H * W * CIN;             // 0.28 MiB weights
    xpose_kernel<<<dim3(NIMG * H), dim3(256), 0, stream>>>(x, xt);
    wprep_kernel<<<dim3((OCH * K_TOT + 255) / 256), dim3(256), 0, stream>>>(wsrc, bp);
    gemm_kernel<<<dim3((M_TOT + BM - 1) / BM), dim3(256), 0, stream>>>(xt, bp, bias, out);
}

// Round 2
// 46.400 us; speedup vs baseline: 1.5044x; 1.5044x over previous
//
#include <hip/hip_runtime.h>
#include <stdint.h>

#define AS_G __attribute__((address_space(1)))
#define AS_L __attribute__((address_space(3)))

typedef __bf16 bf16x8 __attribute__((ext_vector_type(8)));
typedef float  f32x4  __attribute__((ext_vector_type(4)));

static constexpr int NIMG = 16, CIN = 128, H = 64, W = 64, OCH = 128;
static constexpr int HO = 62, WO = 62;
static constexpr int PIX = HO * WO;            // 3844
static constexpr int M_TOT = NIMG * PIX;       // 61504
static constexpr int K_TOT = CIN * 9;          // 1152
static constexpr int BM = 64, BK = 64;
static constexpr int KSTEPS = K_TOT / BK;      // 18

__device__ __forceinline__ unsigned short f2bf(float f) {
    union { float f; uint32_t u; } v; v.f = f;
    uint32_t u = v.u;
    return (unsigned short)((u + 0x7FFFu + ((u >> 16) & 1u)) >> 16);
}

// NCHW fp32 -> NHWC bf16. One block per (n,h) row.
__global__ __launch_bounds__(256) void xpose_kernel(const float* __restrict__ x,
                                                    unsigned short* __restrict__ xt) {
    __shared__ float lds[CIN][W + 4];
    const int n   = blockIdx.x >> 6;
    const int h   = blockIdx.x & 63;
    const int tid = threadIdx.x;
    {
        const int c  = tid >> 1;
        const int w0 = (tid & 1) * 32;
        const float* src = x + (((size_t)(n * CIN + c) * H + h) * W + w0);
        #pragma unroll
        for (int j = 0; j < 8; ++j) {
            float4 v = *reinterpret_cast<const float4*>(src + j * 4);
            *reinterpret_cast<float4*>(&lds[c][w0 + j * 4]) = v;
        }
    }
    __syncthreads();
    {
        const int w  = tid >> 2;
        const int c0 = (tid & 3) * 32;
        unsigned short* dst = xt + (((size_t)(n * H + h) * W + w) * CIN + c0);
        uint32_t pk[16];
        #pragma unroll
        for (int j = 0; j < 16; ++j) {
            uint32_t lo = f2bf(lds[c0 + 2 * j][w]);
            uint32_t hi = f2bf(lds[c0 + 2 * j + 1][w]);
            pk[j] = lo | (hi << 16);
        }
        #pragma unroll
        for (int j = 0; j < 4; ++j) {
            *reinterpret_cast<uint4*>(dst + j * 8) =
                make_uint4(pk[4 * j], pk[4 * j + 1], pk[4 * j + 2], pk[4 * j + 3]);
        }
    }
}

// weight [O][c*9+t] fp32 -> Bp [O][t*128+c] bf16
__global__ __launch_bounds__(256) void wprep_kernel(const float* __restrict__ wsrc,
                                                    unsigned short* __restrict__ bpd) {
    int tid = blockIdx.x * 256 + threadIdx.x;
    if (tid >= OCH * K_TOT) return;
    int o  = tid / K_TOT;
    int kp = tid - o * K_TOT;   // kp = t*128 + c
    int t  = kp >> 7;
    int c  = kp & 127;
    bpd[tid] = f2bf(wsrc[o * K_TOT + c * 9 + t]);
}

// Implicit-GEMM conv: C[m][o] = sum_k A[m][k]*W[o][k], m=(n,y,x), k=(t,c)
// MFMA operands SWAPPED (W as A-operand) so D cols = m -> coalesced stores.
__global__ __launch_bounds__(256) void gemm_kernel(const unsigned short* __restrict__ xt,
                                                   const unsigned short* __restrict__ bp,
                                                   const float* __restrict__ bias,
                                                   float* __restrict__ out) {
    __shared__ alignas(16) unsigned short As[BM * BK];   // 8 KB, XOR-swizzled
    __shared__ alignas(16) unsigned short Bs[OCH * BK];  // 16 KB, XOR-swizzled
    const int tid  = threadIdx.x;
    const int wv   = tid >> 6;
    const int lane = tid & 63;
    const int m0   = blockIdx.x * BM;   // 961*64 == M_TOT exactly: no bounds checks

    // slot s covers LDS bytes [s*16, s*16+16); row = s>>3 (8 slots per 128B row)
    // phys_byte = row*128 + (colbyte ^ ((row&7)<<4)); row&7 == lane>>3:
    const int csel = ((lane & 7) ^ (lane >> 3)) * 8;   // source col offset, elems
    int aBase[2], bBase[4];
    #pragma unroll
    for (int i = 0; i < 2; ++i) {
        int row = (wv * 2 + i) * 8 + (lane >> 3);      // m-row 0..63
        int m = m0 + row;
        int n  = m / PIX;
        int r  = m - n * PIX;
        int y  = r / WO;
        int xx = r - y * WO;
        aBase[i] = ((n * H + y) * W + xx) * CIN;       // NHWC elem index, tap 0
    }
    #pragma unroll
    for (int i = 0; i < 4; ++i) {
        int row = (wv * 4 + i) * 8 + (lane >> 3);      // o-row 0..127
        bBase[i] = row * K_TOT;
    }

    // compute-side fragment addresses
    const int wr = wv >> 1, wc = wv & 1;               // wave tile: m 32, o 64
    const int lr = lane & 15, lq = lane >> 4;
    const int aRow = (wr * 32 + lr) * 128;             // byte offset of m-row
    const int bRow = (wc * 64 + lr) * 128;             // byte offset of o-row
    int colx[2];
    #pragma unroll
    for (int ks = 0; ks < 2; ++ks)
        colx[ks] = (ks * 64 + lq * 16) ^ ((lane & 7) << 4);

    f32x4 acc[2][4];
    #pragma unroll
    for (int a = 0; a < 2; ++a)
        #pragma unroll
        for (int b = 0; b < 4; ++b)
            acc[a][b] = (f32x4){0.f, 0.f, 0.f, 0.f};

    const char* AsB = (const char*)As;
    const char* BsB = (const char*)Bs;

    for (int step = 0; step < KSTEPS; ++step) {
        const int t  = step >> 1;
        const int c0 = (step & 1) * 64;
        const int tapoff = (t / 3) * (W * CIN) + (t % 3) * CIN + c0;
        const int kb = step * BK;
        #pragma unroll
        for (int i = 0; i < 2; ++i)
            __builtin_amdgcn_global_load_lds(
                (AS_G unsigned int*)(xt + aBase[i] + tapoff + csel),
                (AS_L unsigned int*)((char*)As + (wv * 2 + i) * 1024),
                16, 0, 0);
        #pragma unroll
        for (int i = 0; i < 4; ++i)
            __builtin_amdgcn_global_load_lds(
                (AS_G unsigned int*)(bp + bBase[i] + kb + csel),
                (AS_L unsigned int*)((char*)Bs + (wv * 4 + i) * 1024),
                16, 0, 0);
        __syncthreads();
        #pragma unroll
        for (int ks = 0; ks < 2; ++ks) {
            bf16x8 af[2], bfr[4];
            #pragma unroll
            for (int mi = 0; mi < 2; ++mi)
                af[mi] = *(const bf16x8*)(AsB + aRow + mi * 2048 + colx[ks]);
            #pragma unroll
            for (int ni = 0; ni < 4; ++ni)
                bfr[ni] = *(const bf16x8*)(BsB + bRow + ni * 2048 + colx[ks]);
            #pragma unroll
            for (int mi = 0; mi < 2; ++mi)
                #pragma unroll
                for (int ni = 0; ni < 4; ++ni)
                    acc[mi][ni] = __builtin_amdgcn_mfma_f32_16x16x32_bf16(
                        bfr[ni], af[mi], acc[mi][ni], 0, 0, 0);   // D rows=o, cols=m
        }
        __syncthreads();
    }

    // epilogue: D col = lane&15 = m (consecutive!), row = (lane>>4)*4+j = o
    f32x4 bv[4];
    #pragma unroll
    for (int ni = 0; ni < 4; ++ni)
        bv[ni] = *(const f32x4*)(bias + wc * 64 + ni * 16 + lq * 4);
    #pragma unroll
    for (int mi = 0; mi < 2; ++mi) {
        int m = m0 + wr * 32 + mi * 16 + lr;
        int n  = m / PIX;
        int r  = m - n * PIX;
        int y  = r / WO;
        int xx = r - y * WO;
        float* ob = out + (size_t)n * OCH * PIX + y * WO + xx;
        #pragma unroll
        for (int ni = 0; ni < 4; ++ni)
            #pragma unroll
            for (int j = 0; j < 4; ++j) {
                int o = wc * 64 + ni * 16 + lq * 4 + j;
                ob[(size_t)o * PIX] = acc[mi][ni][j] + bv[ni][j];
            }
    }
}

extern "C" void kernel_launch(void* const* d_in, const int* in_sizes, int n_in,
                              void* d_out, int out_size, void* d_ws, size_t ws_size,
                              hipStream_t stream) {
    const float* x    = (const float*)d_in[0];
    const float* wsrc = (const float*)d_in[1];
    const float* bias = (const float*)d_in[2];
    float* out = (float*)d_out;
    unsigned short* xt = (unsigned short*)d_ws;
    unsigned short* bp = xt + (size_t)NIMG * H * W * CIN;
    xpose_kernel<<<dim3(NIMG * H), dim3(256), 0, stream>>>(x, xt);
    wprep_kernel<<<dim3((OCH * K_TOT + 255) / 256), dim3(256), 0, stream>>>(wsrc, bp);
    gemm_kernel<<<dim3(M_TOT / BM), dim3(256), 0, stream>>>(xt, bp, bias, out);
}